// Round 1
// baseline (82.038 us; speedup 1.0000x reference)
//
#include <hip/hip_runtime.h>
#include <math.h>

static constexpr int B_ = 4;
static constexpr int L_ = 256;
static constexpr int K_ = 256;
static constexpr int H_ = 768;
static constexpr float INV_TEMPER = 0.03608439182435161f; // 1/sqrt(768)

// ---------------------------------------------------------------------------
// Kernel A: gather key embedding rows and transpose into E_T[b][h][k]
// so the score kernel reads coalesced along k.
// grid (K/64, H/64, B), block 256.
// ---------------------------------------------------------------------------
__global__ __launch_bounds__(256)
void k_gather_keys_T(const int* __restrict__ key_seq,
                     const float* __restrict__ key_emb,
                     float* __restrict__ ET) {
  __shared__ float tile[64][65];   // +1 pad: conflict-free transpose
  const int kb   = blockIdx.x * 64;
  const int hb   = blockIdx.y * 64;
  const int b    = blockIdx.z;
  const int t    = threadIdx.x;
  const int sub  = t >> 6;         // 0..3
  const int lane = t & 63;

#pragma unroll
  for (int p = 0; p < 16; ++p) {
    const int kl  = p * 4 + sub;
    const int row = key_seq[b * K_ + kb + kl];           // wave-uniform
    tile[kl][lane] = key_emb[(size_t)row * H_ + hb + lane]; // coalesced read
  }
  __syncthreads();
#pragma unroll
  for (int p = 0; p < 16; ++p) {
    const int hl = p * 4 + sub;
    // coalesced write along k
    ET[((size_t)b * H_ + hb + hl) * K_ + kb + lane] = tile[lane][hl];
  }
}

// ---------------------------------------------------------------------------
// Kernel B: scores + masked softmax, fused.
// Block handles (b, 4 l-rows). 256 threads = 64 k-quads x 4 h-chunks.
// Each thread: float4 over k, 4 l-rows, 192 h iterations -> 16 FMA / 16B load.
// grid (L/4, B), block 256.
// ---------------------------------------------------------------------------
__global__ __launch_bounds__(256)
void k_scores_softmax(const float* __restrict__ hidden,
                      const float* __restrict__ ET,
                      const int* __restrict__ mask,
                      float* __restrict__ P) {
  __shared__ float  hid[4 * H_];    // 12 KB
  __shared__ float4 part[4][256];   // 16 KB  [l][hq*64+kq]

  const int l0 = blockIdx.x * 4;
  const int b  = blockIdx.y;
  const int t  = threadIdx.x;

  // stage 4 hidden rows
  const float* hsrc = hidden + ((size_t)b * L_ + l0) * H_;
  for (int i = t; i < 4 * H_; i += 256) hid[i] = hsrc[i];
  __syncthreads();

  const int kq = t & 63;   // k-quad: k = kq*4 .. kq*4+3
  const int hq = t >> 6;   // h-chunk: h in [hq*192, hq*192+192)

  float4 acc[4];
#pragma unroll
  for (int l = 0; l < 4; ++l) acc[l] = make_float4(0.f, 0.f, 0.f, 0.f);

  const float* etp = ET + (size_t)b * H_ * K_ + (size_t)(hq * 192) * K_ + kq * 4;
  const int hbase = hq * 192;
#pragma unroll 4
  for (int hh = 0; hh < 192; ++hh) {
    const float4 e = *reinterpret_cast<const float4*>(etp + (size_t)hh * K_);
#pragma unroll
    for (int l = 0; l < 4; ++l) {
      const float hv = hid[l * H_ + hbase + hh];  // LDS broadcast
      acc[l].x += hv * e.x;
      acc[l].y += hv * e.y;
      acc[l].z += hv * e.z;
      acc[l].w += hv * e.w;
    }
  }
#pragma unroll
  for (int l = 0; l < 4; ++l) part[l][t] = acc[l];
  __syncthreads();

  // remap: thread -> (l2, kq2); wave wid == l2 covers all 256 k for that l.
  const int kq2 = t & 63;
  const int l2  = t >> 6;
  float4 a = part[l2][kq2];
  const float4 b1 = part[l2][64 + kq2];
  const float4 c  = part[l2][128 + kq2];
  const float4 d  = part[l2][192 + kq2];
  a.x += b1.x + c.x + d.x;
  a.y += b1.y + c.y + d.y;
  a.z += b1.z + c.z + d.z;
  a.w += b1.w + c.w + d.w;

  const int lrow = l0 + l2;
  const int4 m4 = *reinterpret_cast<const int4*>(
      mask + ((size_t)b * L_ + lrow) * K_ + kq2 * 4);
  float4 ex;
  ex.x = (m4.x > 0) ? expf(a.x * INV_TEMPER) : 0.f;
  ex.y = (m4.y > 0) ? expf(a.y * INV_TEMPER) : 0.f;
  ex.z = (m4.z > 0) ? expf(a.z * INV_TEMPER) : 0.f;
  ex.w = (m4.w > 0) ? expf(a.w * INV_TEMPER) : 0.f;

  float s = ex.x + ex.y + ex.z + ex.w;
#pragma unroll
  for (int off = 32; off > 0; off >>= 1) s += __shfl_down(s, off);
  const float tot = __shfl(s, 0) + 1e-10f;

  float4 p4;
  p4.x = ex.x / tot;
  p4.y = ex.y / tot;
  p4.z = ex.z / tot;
  p4.w = ex.w / tot;
  *reinterpret_cast<float4*>(P + ((size_t)b * L_ + lrow) * K_ + kq2 * 4) = p4;
}

// ---------------------------------------------------------------------------
// Kernel C: o = sum_k p * V[idx] + hidden, skipping p==0 (mask) via
// deterministic LDS compaction. Block per (b,l); 384 threads = 2 k-slices
// x 192 h-lanes (float4).
// grid (L, B), block 384.
// ---------------------------------------------------------------------------
__global__ __launch_bounds__(384)
void k_pv_add(const float* __restrict__ hidden,
              const int* __restrict__ vmat,
              const float* __restrict__ P,
              const float* __restrict__ vtab,
              float* __restrict__ out) {
  __shared__ float  pw[K_];
  __shared__ int    vidx[K_];
  __shared__ int    wcounts[4];
  __shared__ float4 osum4[H_ / 4];

  const int l = blockIdx.x;
  const int b = blockIdx.y;
  const int t = threadIdx.x;
  const int lane = t & 63;
  const int wid  = t >> 6;
  const size_t rowoff = ((size_t)b * L_ + l) * K_;

  // deterministic compaction of nonzero p
  float pval = 0.f;
  bool pred = false;
  unsigned long long mball = 0;
  if (t < K_) {
    pval = P[rowoff + t];
    pred = (pval != 0.f);
    mball = __ballot(pred);                      // waves 0..3 fully active
    if (lane == 0) wcounts[wid] = (int)__popcll(mball);
  }
  __syncthreads();
  const int n = wcounts[0] + wcounts[1] + wcounts[2] + wcounts[3];
  if (t < K_ && pred) {
    int base = 0;
#pragma unroll
    for (int w = 0; w < 4; ++w)
      if (w < wid) base += wcounts[w];
    const int pos = base + (int)__popcll(mball & ((1ull << lane) - 1ull));
    pw[pos]   = pval;
    vidx[pos] = vmat[rowoff + t];
  }
  __syncthreads();

  const int slice = t / 192;  // 0 or 1 (waves homogeneous)
  const int h4    = t % 192;

  float4 acc = make_float4(0.f, 0.f, 0.f, 0.f);
  for (int j = slice; j < n; j += 2) {
    const float w = pw[j];                        // LDS broadcast
    const float4 v = *reinterpret_cast<const float4*>(
        vtab + (size_t)vidx[j] * H_ + h4 * 4);    // coalesced 3KB row
    acc.x += w * v.x;
    acc.y += w * v.y;
    acc.z += w * v.z;
    acc.w += w * v.w;
  }

  if (slice == 0) osum4[h4] = acc;
  __syncthreads();
  if (slice == 1) {
    const float4 o  = osum4[h4];
    const float4 hd = reinterpret_cast<const float4*>(
        hidden + ((size_t)b * L_ + l) * H_)[h4];
    float4 r;
    r.x = acc.x + o.x + hd.x;
    r.y = acc.y + o.y + hd.y;
    r.z = acc.z + o.z + hd.z;
    r.w = acc.w + o.w + hd.w;
    reinterpret_cast<float4*>(out + ((size_t)b * L_ + l) * H_)[h4] = r;
  }
}

// ---------------------------------------------------------------------------
extern "C" void kernel_launch(void* const* d_in, const int* in_sizes, int n_in,
                              void* d_out, int out_size, void* d_ws, size_t ws_size,
                              hipStream_t stream) {
  (void)in_sizes; (void)n_in; (void)out_size; (void)ws_size;
  const float* hidden  = (const float*)d_in[0];
  const int*   key_seq = (const int*)d_in[1];
  const int*   vmat    = (const int*)d_in[2];
  const int*   mask    = (const int*)d_in[3];
  const float* key_emb = (const float*)d_in[4];
  const float* val_emb = (const float*)d_in[5];
  float* out = (float*)d_out;

  float* ET = (float*)d_ws;                         // B*H*K floats = 3 MB
  float* P  = ET + (size_t)B_ * H_ * K_;            // B*L*K floats = 1 MB

  k_gather_keys_T<<<dim3(K_ / 64, H_ / 64, B_), 256, 0, stream>>>(
      key_seq, key_emb, ET);
  k_scores_softmax<<<dim3(L_ / 4, B_), 256, 0, stream>>>(
      hidden, ET, mask, P);
  k_pv_add<<<dim3(L_, B_), 384, 0, stream>>>(
      hidden, vmat, P, val_emb, out);
}

// Round 2
// 62.533 us; speedup vs baseline: 1.3119x; 1.3119x over previous
//
#include <hip/hip_runtime.h>
#include <math.h>

static constexpr int B_ = 4;
static constexpr int L_ = 256;
static constexpr int K_ = 256;
static constexpr int H_ = 768;
static constexpr int VAL_SIZE_ = 10000;
static constexpr float INV_TEMPER = 0.03608439182435161f; // 1/sqrt(768)

// bf16 helpers (OCP bf16 semantics, RNE, inputs are finite normals)
__device__ __forceinline__ unsigned bf16_rne(float f) {
  unsigned x = __float_as_uint(f);
  return (x + 0x7fffu + ((x >> 16) & 1u)) >> 16;
}
__device__ __forceinline__ float bf_lo(unsigned u) { return __uint_as_float(u << 16); }
__device__ __forceinline__ float bf_hi(unsigned u) { return __uint_as_float(u & 0xffff0000u); }

static constexpr int TBLK = (K_ / 64) * (H_ / 64) * B_;        // 192 transpose blocks
static constexpr int CBLK = (VAL_SIZE_ * H_) / (256 * 8);      // 3750 convert blocks

// ---------------------------------------------------------------------------
// Kernel A+prep (fused): blocks [0,TBLK) gather+transpose key rows into
// bf16 ET16[b][h][k]; blocks [TBLK, TBLK+CBLK) convert val_emb -> bf16 VT16.
// block 256.
// ---------------------------------------------------------------------------
__global__ __launch_bounds__(256)
void k_prep(const int* __restrict__ key_seq,
            const float* __restrict__ key_emb,
            const float* __restrict__ vtab,
            unsigned short* __restrict__ ET16,
            unsigned short* __restrict__ VT16) {
  __shared__ float tile[64][65];
  const int t = threadIdx.x;

  if (blockIdx.x >= TBLK) {
    // ---- val table f32 -> bf16, 8 elems/thread, exact-cover grid ----
    const size_t e0 = ((size_t)(blockIdx.x - TBLK) * 256 + t) * 8;
    const float4 a = *reinterpret_cast<const float4*>(vtab + e0);
    const float4 c = *reinterpret_cast<const float4*>(vtab + e0 + 4);
    uint4 o;
    o.x = bf16_rne(a.x) | (bf16_rne(a.y) << 16);
    o.y = bf16_rne(a.z) | (bf16_rne(a.w) << 16);
    o.z = bf16_rne(c.x) | (bf16_rne(c.y) << 16);
    o.w = bf16_rne(c.z) | (bf16_rne(c.w) << 16);
    *reinterpret_cast<uint4*>(VT16 + e0) = o;
    return;
  }

  // ---- key gather + transpose ----
  const int blk  = blockIdx.x;
  const int kb   = (blk % (K_ / 64)) * 64;
  const int hb   = ((blk / (K_ / 64)) % (H_ / 64)) * 64;
  const int b    = blk / ((K_ / 64) * (H_ / 64));
  const int sub  = t >> 6;         // 0..3
  const int lane = t & 63;

#pragma unroll
  for (int p = 0; p < 16; ++p) {
    const int kl  = p * 4 + sub;
    const int row = key_seq[b * K_ + kb + kl];              // wave-uniform
    tile[kl][lane] = key_emb[(size_t)row * H_ + hb + lane]; // coalesced
  }
  __syncthreads();
#pragma unroll
  for (int p = 0; p < 16; ++p) {
    const int hl = p * 4 + sub;
    ET16[((size_t)b * H_ + hb + hl) * K_ + kb + lane] =
        (unsigned short)bf16_rne(tile[lane][hl]);
  }
}

// ---------------------------------------------------------------------------
// Kernel B: scores + masked softmax, fused. ET in bf16.
// Block handles (b, 4 l-rows). 256 threads = 64 k-quads x 4 h-chunks.
// grid (L/4, B), block 256.
// ---------------------------------------------------------------------------
__global__ __launch_bounds__(256)
void k_scores_softmax(const float* __restrict__ hidden,
                      const unsigned short* __restrict__ ET16,
                      const int* __restrict__ mask,
                      float* __restrict__ P) {
  __shared__ float  hid[4 * H_];    // 12 KB
  __shared__ float4 part[4][256];   // 16 KB

  const int l0 = blockIdx.x * 4;
  const int b  = blockIdx.y;
  const int t  = threadIdx.x;

  const float* hsrc = hidden + ((size_t)b * L_ + l0) * H_;
  for (int i = t; i < 4 * H_; i += 256) hid[i] = hsrc[i];
  __syncthreads();

  const int kq = t & 63;
  const int hq = t >> 6;

  float4 acc[4];
#pragma unroll
  for (int l = 0; l < 4; ++l) acc[l] = make_float4(0.f, 0.f, 0.f, 0.f);

  const unsigned short* etp =
      ET16 + (size_t)b * H_ * K_ + (size_t)(hq * 192) * K_ + kq * 4;
  const int hbase = hq * 192;
#pragma unroll 4
  for (int hh = 0; hh < 192; ++hh) {
    const uint2 e = *reinterpret_cast<const uint2*>(etp + (size_t)hh * K_);
    const float e0 = bf_lo(e.x), e1 = bf_hi(e.x);
    const float e2 = bf_lo(e.y), e3 = bf_hi(e.y);
#pragma unroll
    for (int l = 0; l < 4; ++l) {
      const float hv = hid[l * H_ + hbase + hh];  // LDS broadcast
      acc[l].x += hv * e0;
      acc[l].y += hv * e1;
      acc[l].z += hv * e2;
      acc[l].w += hv * e3;
    }
  }
#pragma unroll
  for (int l = 0; l < 4; ++l) part[l][t] = acc[l];
  __syncthreads();

  const int kq2 = t & 63;
  const int l2  = t >> 6;
  float4 a = part[l2][kq2];
  const float4 b1 = part[l2][64 + kq2];
  const float4 c  = part[l2][128 + kq2];
  const float4 d  = part[l2][192 + kq2];
  a.x += b1.x + c.x + d.x;
  a.y += b1.y + c.y + d.y;
  a.z += b1.z + c.z + d.z;
  a.w += b1.w + c.w + d.w;

  const int lrow = l0 + l2;
  const int4 m4 = *reinterpret_cast<const int4*>(
      mask + ((size_t)b * L_ + lrow) * K_ + kq2 * 4);
  float4 ex;
  ex.x = (m4.x > 0) ? expf(a.x * INV_TEMPER) : 0.f;
  ex.y = (m4.y > 0) ? expf(a.y * INV_TEMPER) : 0.f;
  ex.z = (m4.z > 0) ? expf(a.z * INV_TEMPER) : 0.f;
  ex.w = (m4.w > 0) ? expf(a.w * INV_TEMPER) : 0.f;

  float s = ex.x + ex.y + ex.z + ex.w;
#pragma unroll
  for (int off = 32; off > 0; off >>= 1) s += __shfl_down(s, off);
  const float tot = __shfl(s, 0) + 1e-10f;

  float4 p4;
  p4.x = ex.x / tot;
  p4.y = ex.y / tot;
  p4.z = ex.z / tot;
  p4.w = ex.w / tot;
  *reinterpret_cast<float4*>(P + ((size_t)b * L_ + lrow) * K_ + kq2 * 4) = p4;
}

// ---------------------------------------------------------------------------
// Kernel C: o = sum_k p * V16[idx] + hidden, skipping p==0 (mask) via
// deterministic compaction. bf16 value rows (1.5 KB each).
// grid (L, B), block 384 = 2 k-slices x 192 h-lanes (4 elems each).
// ---------------------------------------------------------------------------
__global__ __launch_bounds__(384)
void k_pv_add(const float* __restrict__ hidden,
              const int* __restrict__ vmat,
              const float* __restrict__ P,
              const unsigned short* __restrict__ VT16,
              float* __restrict__ out) {
  __shared__ float  pw[K_];
  __shared__ int    vidx[K_];
  __shared__ int    wcounts[4];
  __shared__ float4 osum4[H_ / 4];

  const int l = blockIdx.x;
  const int b = blockIdx.y;
  const int t = threadIdx.x;
  const int lane = t & 63;
  const int wid  = t >> 6;
  const size_t rowoff = ((size_t)b * L_ + l) * K_;

  // deterministic compaction of nonzero p
  float pval = 0.f;
  bool pred = false;
  unsigned long long mball = 0;
  if (t < K_) {
    pval = P[rowoff + t];
    pred = (pval != 0.f);
    mball = __ballot(pred);                      // waves 0..3 fully active
    if (lane == 0) wcounts[wid] = (int)__popcll(mball);
  }
  __syncthreads();
  const int n = wcounts[0] + wcounts[1] + wcounts[2] + wcounts[3];
  if (t < K_ && pred) {
    int base = 0;
#pragma unroll
    for (int w = 0; w < 4; ++w)
      if (w < wid) base += wcounts[w];
    const int pos = base + (int)__popcll(mball & ((1ull << lane) - 1ull));
    pw[pos]   = pval;
    vidx[pos] = vmat[rowoff + t];
  }
  __syncthreads();

  const int slice = t / 192;  // 0 or 1 (wave-homogeneous)
  const int h4    = t % 192;

  float4 acc = make_float4(0.f, 0.f, 0.f, 0.f);
#pragma unroll 4
  for (int j = slice; j < n; j += 2) {
    const float w = pw[j];                        // LDS broadcast
    const uint2 v = *reinterpret_cast<const uint2*>(
        VT16 + (size_t)vidx[j] * H_ + h4 * 4);    // coalesced bf16 row
    acc.x += w * bf_lo(v.x);
    acc.y += w * bf_hi(v.x);
    acc.z += w * bf_lo(v.y);
    acc.w += w * bf_hi(v.y);
  }

  if (slice == 0) osum4[h4] = acc;
  __syncthreads();
  if (slice == 1) {
    const float4 o  = osum4[h4];
    const float4 hd = reinterpret_cast<const float4*>(
        hidden + ((size_t)b * L_ + l) * H_)[h4];
    float4 r;
    r.x = acc.x + o.x + hd.x;
    r.y = acc.y + o.y + hd.y;
    r.z = acc.z + o.z + hd.z;
    r.w = acc.w + o.w + hd.w;
    reinterpret_cast<float4*>(out + ((size_t)b * L_ + l) * H_)[h4] = r;
  }
}

// ---------------------------------------------------------------------------
extern "C" void kernel_launch(void* const* d_in, const int* in_sizes, int n_in,
                              void* d_out, int out_size, void* d_ws, size_t ws_size,
                              hipStream_t stream) {
  (void)in_sizes; (void)n_in; (void)out_size; (void)ws_size;
  const float* hidden  = (const float*)d_in[0];
  const int*   key_seq = (const int*)d_in[1];
  const int*   vmat    = (const int*)d_in[2];
  const int*   mask    = (const int*)d_in[3];
  const float* key_emb = (const float*)d_in[4];
  const float* val_emb = (const float*)d_in[5];
  float* out = (float*)d_out;

  // ws layout (all 16B-aligned):
  //   VT16: VAL_SIZE*H ushort = 15,360,000 B  (divisible by 256)
  //   ET16: B*H*K ushort      =  1,572,864 B
  //   P   : B*L*K float       =  1,048,576 B
  unsigned short* VT16 = (unsigned short*)d_ws;
  unsigned short* ET16 = VT16 + (size_t)VAL_SIZE_ * H_;
  float*          P    = (float*)(ET16 + (size_t)B_ * H_ * K_);

  k_prep<<<TBLK + CBLK, 256, 0, stream>>>(key_seq, key_emb, val_emb, ET16, VT16);
  k_scores_softmax<<<dim3(L_ / 4, B_), 256, 0, stream>>>(hidden, ET16, mask, P);
  k_pv_add<<<dim3(L_, B_), 384, 0, stream>>>(hidden, vmat, P, VT16, out);
}

// Round 3
// 61.005 us; speedup vs baseline: 1.3448x; 1.0250x over previous
//
#include <hip/hip_runtime.h>
#include <math.h>

static constexpr int B_ = 4;
static constexpr int L_ = 256;
static constexpr int K_ = 256;
static constexpr int H_ = 768;
static constexpr int VAL_SIZE_ = 10000;
static constexpr float INV_TEMPER = 0.03608439182435161f; // 1/sqrt(768)

// bf16 helpers (RNE)
__device__ __forceinline__ unsigned bf16_rne(float f) {
  unsigned x = __float_as_uint(f);
  return (x + 0x7fffu + ((x >> 16) & 1u)) >> 16;
}
__device__ __forceinline__ float bf_lo(unsigned u) { return __uint_as_float(u << 16); }
__device__ __forceinline__ float bf_hi(unsigned u) { return __uint_as_float(u & 0xffff0000u); }

static constexpr int TBLK = (K_ / 64) * (H_ / 64) * B_;   // 192 transpose blocks
static constexpr int SBLK = (L_ / 4) * B_;                // 256 score blocks
static constexpr int CBLK = (VAL_SIZE_ * H_) / (256 * 8); // 3750 convert blocks

// ---------------------------------------------------------------------------
// Kernel 1: gather key embedding rows, transpose to bf16 ET16[b][h][k].
// grid TBLK, block 256.
// ---------------------------------------------------------------------------
__global__ __launch_bounds__(256)
void k_gather_keys_T(const int* __restrict__ key_seq,
                     const float* __restrict__ key_emb,
                     unsigned short* __restrict__ ET16) {
  __shared__ float tile[64][65];
  const int blk  = blockIdx.x;
  const int kb   = (blk % (K_ / 64)) * 64;
  const int hb   = ((blk / (K_ / 64)) % (H_ / 64)) * 64;
  const int b    = blk / ((K_ / 64) * (H_ / 64));
  const int t    = threadIdx.x;
  const int sub  = t >> 6;
  const int lane = t & 63;

#pragma unroll
  for (int p = 0; p < 16; ++p) {
    const int kl  = p * 4 + sub;
    const int row = key_seq[b * K_ + kb + kl];              // wave-uniform
    tile[kl][lane] = key_emb[(size_t)row * H_ + hb + lane]; // coalesced
  }
  __syncthreads();
#pragma unroll
  for (int p = 0; p < 16; ++p) {
    const int hl = p * 4 + sub;
    ET16[((size_t)b * H_ + hb + hl) * K_ + kb + lane] =
        (unsigned short)bf16_rne(tile[lane][hl]);
  }
}

// ---------------------------------------------------------------------------
// Kernel 2: scores + masked softmax (blocks [0,SBLK)), val-table f32->bf16
// conversion (blocks [SBLK, SBLK+CBLK)) riding the same grid so its HBM
// traffic overlaps the scores' L2/VALU work. block 256.
// ---------------------------------------------------------------------------
__global__ __launch_bounds__(256)
void k_scores_convert(const float* __restrict__ hidden,
                      const unsigned short* __restrict__ ET16,
                      const int* __restrict__ mask,
                      const float* __restrict__ vtab,
                      float* __restrict__ P,
                      unsigned short* __restrict__ VT16) {
  __shared__ float  hid[4 * H_];    // 12 KB
  __shared__ float4 part[4][256];   // 16 KB
  const int t = threadIdx.x;

  if (blockIdx.x >= SBLK) {
    // ---- val table f32 -> bf16, 8 elems/thread, exact-cover ----
    const size_t e0 = ((size_t)(blockIdx.x - SBLK) * 256 + t) * 8;
    const float4 a = *reinterpret_cast<const float4*>(vtab + e0);
    const float4 c = *reinterpret_cast<const float4*>(vtab + e0 + 4);
    uint4 o;
    o.x = bf16_rne(a.x) | (bf16_rne(a.y) << 16);
    o.y = bf16_rne(a.z) | (bf16_rne(a.w) << 16);
    o.z = bf16_rne(c.x) | (bf16_rne(c.y) << 16);
    o.w = bf16_rne(c.z) | (bf16_rne(c.w) << 16);
    *reinterpret_cast<uint4*>(VT16 + e0) = o;
    return;
  }

  const int l0 = (blockIdx.x % (L_ / 4)) * 4;
  const int b  = blockIdx.x / (L_ / 4);

  const float* hsrc = hidden + ((size_t)b * L_ + l0) * H_;
  for (int i = t; i < 4 * H_; i += 256) hid[i] = hsrc[i];
  __syncthreads();

  const int kq = t & 63;
  const int hq = t >> 6;

  float4 acc[4];
#pragma unroll
  for (int l = 0; l < 4; ++l) acc[l] = make_float4(0.f, 0.f, 0.f, 0.f);

  const unsigned short* etp =
      ET16 + (size_t)b * H_ * K_ + (size_t)(hq * 192) * K_ + kq * 4;
  const int hbase = hq * 192;
#pragma unroll 4
  for (int hh = 0; hh < 192; ++hh) {
    const uint2 e = *reinterpret_cast<const uint2*>(etp + (size_t)hh * K_);
    const float e0 = bf_lo(e.x), e1 = bf_hi(e.x);
    const float e2 = bf_lo(e.y), e3 = bf_hi(e.y);
#pragma unroll
    for (int l = 0; l < 4; ++l) {
      const float hv = hid[l * H_ + hbase + hh];  // LDS broadcast
      acc[l].x += hv * e0;
      acc[l].y += hv * e1;
      acc[l].z += hv * e2;
      acc[l].w += hv * e3;
    }
  }
#pragma unroll
  for (int l = 0; l < 4; ++l) part[l][t] = acc[l];
  __syncthreads();

  const int kq2 = t & 63;
  const int l2  = t >> 6;
  float4 a = part[l2][kq2];
  const float4 b1 = part[l2][64 + kq2];
  const float4 c  = part[l2][128 + kq2];
  const float4 d  = part[l2][192 + kq2];
  a.x += b1.x + c.x + d.x;
  a.y += b1.y + c.y + d.y;
  a.z += b1.z + c.z + d.z;
  a.w += b1.w + c.w + d.w;

  const int lrow = l0 + l2;
  const int4 m4 = *reinterpret_cast<const int4*>(
      mask + ((size_t)b * L_ + lrow) * K_ + kq2 * 4);
  float4 ex;
  ex.x = (m4.x > 0) ? expf(a.x * INV_TEMPER) : 0.f;
  ex.y = (m4.y > 0) ? expf(a.y * INV_TEMPER) : 0.f;
  ex.z = (m4.z > 0) ? expf(a.z * INV_TEMPER) : 0.f;
  ex.w = (m4.w > 0) ? expf(a.w * INV_TEMPER) : 0.f;

  float s = ex.x + ex.y + ex.z + ex.w;
#pragma unroll
  for (int off = 32; off > 0; off >>= 1) s += __shfl_down(s, off);
  const float tot = __shfl(s, 0) + 1e-10f;

  float4 p4;
  p4.x = ex.x / tot;
  p4.y = ex.y / tot;
  p4.z = ex.z / tot;
  p4.w = ex.w / tot;
  *reinterpret_cast<float4*>(P + ((size_t)b * L_ + lrow) * K_ + kq2 * 4) = p4;
}

// ---------------------------------------------------------------------------
// Kernel 3: o = sum_k p * V16[idx] + hidden, skipping p==0 via deterministic
// compaction. 4 slices x 96 lanes, uint4 (16B = 8 bf16) per lane -> 4 rows
// in flight, 64B/lane outstanding with unroll 4.
// grid (L, B), block 384.
// ---------------------------------------------------------------------------
__global__ __launch_bounds__(384)
void k_pv_add(const float* __restrict__ hidden,
              const int* __restrict__ vmat,
              const float* __restrict__ P,
              const unsigned short* __restrict__ VT16,
              float* __restrict__ out) {
  __shared__ float pw[K_];
  __shared__ int   vidx[K_];
  __shared__ int   wcounts[4];
  __shared__ float osum[3][H_];   // slices 0..2; slice 3 keeps regs

  const int l = blockIdx.x;
  const int b = blockIdx.y;
  const int t = threadIdx.x;
  const int lane = t & 63;
  const int wid  = t >> 6;
  const size_t rowoff = ((size_t)b * L_ + l) * K_;

  // deterministic compaction of nonzero p (waves 0..3 fully active)
  float pval = 0.f;
  bool pred = false;
  unsigned long long mball = 0;
  if (t < K_) {
    pval = P[rowoff + t];
    pred = (pval != 0.f);
    mball = __ballot(pred);
    if (lane == 0) wcounts[wid] = (int)__popcll(mball);
  }
  __syncthreads();
  const int n = wcounts[0] + wcounts[1] + wcounts[2] + wcounts[3];
  if (t < K_ && pred) {
    int base = 0;
#pragma unroll
    for (int w = 0; w < 4; ++w)
      if (w < wid) base += wcounts[w];
    const int pos = base + (int)__popcll(mball & ((1ull << lane) - 1ull));
    pw[pos]   = pval;
    vidx[pos] = vmat[rowoff + t];
  }
  __syncthreads();

  const int slice = t / 96;   // 0..3
  const int g     = t % 96;   // h-lane: h in [g*8, g*8+8)

  float acc[8];
#pragma unroll
  for (int i = 0; i < 8; ++i) acc[i] = 0.f;

#pragma unroll 4
  for (int j = slice; j < n; j += 4) {
    const float w = pw[j];                        // LDS (<=2 addrs/wave)
    const uint4 v = *reinterpret_cast<const uint4*>(
        VT16 + (size_t)vidx[j] * H_ + g * 8);     // 16B coalesced
    acc[0] += w * bf_lo(v.x);
    acc[1] += w * bf_hi(v.x);
    acc[2] += w * bf_lo(v.y);
    acc[3] += w * bf_hi(v.y);
    acc[4] += w * bf_lo(v.z);
    acc[5] += w * bf_hi(v.z);
    acc[6] += w * bf_lo(v.w);
    acc[7] += w * bf_hi(v.w);
  }

  if (slice < 3) {
    float4 lo = make_float4(acc[0], acc[1], acc[2], acc[3]);
    float4 hi4 = make_float4(acc[4], acc[5], acc[6], acc[7]);
    *reinterpret_cast<float4*>(&osum[slice][g * 8])     = lo;
    *reinterpret_cast<float4*>(&osum[slice][g * 8 + 4]) = hi4;
  }
  __syncthreads();
  if (slice == 3) {
    const float* hrow = hidden + ((size_t)b * L_ + l) * H_ + g * 8;
    const float4 h0 = *reinterpret_cast<const float4*>(hrow);
    const float4 h1 = *reinterpret_cast<const float4*>(hrow + 4);
    float4 r0, r1;
    r0.x = acc[0] + osum[0][g*8+0] + osum[1][g*8+0] + osum[2][g*8+0] + h0.x;
    r0.y = acc[1] + osum[0][g*8+1] + osum[1][g*8+1] + osum[2][g*8+1] + h0.y;
    r0.z = acc[2] + osum[0][g*8+2] + osum[1][g*8+2] + osum[2][g*8+2] + h0.z;
    r0.w = acc[3] + osum[0][g*8+3] + osum[1][g*8+3] + osum[2][g*8+3] + h0.w;
    r1.x = acc[4] + osum[0][g*8+4] + osum[1][g*8+4] + osum[2][g*8+4] + h1.x;
    r1.y = acc[5] + osum[0][g*8+5] + osum[1][g*8+5] + osum[2][g*8+5] + h1.y;
    r1.z = acc[6] + osum[0][g*8+6] + osum[1][g*8+6] + osum[2][g*8+6] + h1.z;
    r1.w = acc[7] + osum[0][g*8+7] + osum[1][g*8+7] + osum[2][g*8+7] + h1.w;
    float* orow = out + ((size_t)b * L_ + l) * H_ + g * 8;
    *reinterpret_cast<float4*>(orow)     = r0;
    *reinterpret_cast<float4*>(orow + 4) = r1;
  }
}

// ---------------------------------------------------------------------------
extern "C" void kernel_launch(void* const* d_in, const int* in_sizes, int n_in,
                              void* d_out, int out_size, void* d_ws, size_t ws_size,
                              hipStream_t stream) {
  (void)in_sizes; (void)n_in; (void)out_size; (void)ws_size;
  const float* hidden  = (const float*)d_in[0];
  const int*   key_seq = (const int*)d_in[1];
  const int*   vmat    = (const int*)d_in[2];
  const int*   mask    = (const int*)d_in[3];
  const float* key_emb = (const float*)d_in[4];
  const float* val_emb = (const float*)d_in[5];
  float* out = (float*)d_out;

  // ws layout (16B-aligned):
  //   VT16: VAL_SIZE*H ushort = 15,360,000 B
  //   ET16: B*H*K ushort      =  1,572,864 B
  //   P   : B*L*K float       =  1,048,576 B
  unsigned short* VT16 = (unsigned short*)d_ws;
  unsigned short* ET16 = VT16 + (size_t)VAL_SIZE_ * H_;
  float*          P    = (float*)(ET16 + (size_t)B_ * H_ * K_);

  k_gather_keys_T<<<TBLK, 256, 0, stream>>>(key_seq, key_emb, ET16);
  k_scores_convert<<<SBLK + CBLK, 256, 0, stream>>>(hidden, ET16, mask,
                                                    val_emb, P, VT16);
  k_pv_add<<<dim3(L_, B_), 384, 0, stream>>>(hidden, vmat, P, VT16, out);
}

// Round 4
// 48.490 us; speedup vs baseline: 1.6919x; 1.2581x over previous
//
#include <hip/hip_runtime.h>
#include <math.h>

typedef float f32x2 __attribute__((ext_vector_type(2)));

static constexpr int B_ = 4;
static constexpr int L_ = 256;
static constexpr int K_ = 256;
static constexpr int H_ = 768;
static constexpr int VAL_SIZE_ = 10000;
static constexpr float INV_TEMPER = 0.03608439182435161f; // 1/sqrt(768)

// ---------------- bf16 helpers (RNE) ----------------
__device__ __forceinline__ unsigned bf16_rne(float f) {
  unsigned x = __float_as_uint(f);
  return (x + 0x7fffu + ((x >> 16) & 1u)) >> 16;
}
__device__ __forceinline__ float bf_lo(unsigned u) { return __uint_as_float(u << 16); }
__device__ __forceinline__ float bf_hi(unsigned u) { return __uint_as_float(u & 0xffff0000u); }

// ---------------- fp8 e4m3fn (OCP) helpers ----------------
#if __has_builtin(__builtin_amdgcn_cvt_pk_fp8_f32)
#define HW_FP8_ENC 1
#endif
#if __has_builtin(__builtin_amdgcn_cvt_pk_f32_fp8)
#define HW_FP8_DEC 1
#endif

__device__ __forceinline__ unsigned fp8_enc1(float f) {
  unsigned s = (__float_as_uint(f) >> 31) << 7;
  float af = fminf(fabsf(f), 448.0f);
  unsigned em;
  if (af < 0.015625f) {                       // subnormal: multiples of 2^-9
    em = (unsigned)rintf(af * 512.0f);        // 0..8 (8 -> normal 2^-6, ok)
  } else {
    unsigned m = __float_as_uint(af);
    m += 0x7ffffu + ((m >> 20) & 1u);         // RNE to 3-bit mantissa
    em = (m >> 20) - (120u << 3);             // ((E-120)<<3)|mant3
  }
  return s | em;
}
__device__ __forceinline__ float fp8_dec1(unsigned b) {
  unsigned em = b & 0x7fu;
  unsigned sbit = (b & 0x80u) << 24;
  float n = __uint_as_float(sbit | ((em + 960u) << 20));
  float sub = __uint_as_float(sbit | 0x3F800000u) * (float)em * 0.001953125f;
  return em >= 8u ? n : sub;
}
__device__ __forceinline__ unsigned fp8_enc4(float a, float b, float c, float d) {
#ifdef HW_FP8_ENC
  int w = 0;
  w = __builtin_amdgcn_cvt_pk_fp8_f32(a, b, w, false);
  w = __builtin_amdgcn_cvt_pk_fp8_f32(c, d, w, true);
  return (unsigned)w;
#else
  return fp8_enc1(a) | (fp8_enc1(b) << 8) | (fp8_enc1(c) << 16) | (fp8_enc1(d) << 24);
#endif
}
__device__ __forceinline__ void fp8_dec4(unsigned w, float* o) {
#ifdef HW_FP8_DEC
  f32x2 lo = __builtin_amdgcn_cvt_pk_f32_fp8((int)w, false);
  f32x2 hi = __builtin_amdgcn_cvt_pk_f32_fp8((int)w, true);
  o[0] = lo.x; o[1] = lo.y; o[2] = hi.x; o[3] = hi.y;
#else
  o[0] = fp8_dec1(w & 0xffu);
  o[1] = fp8_dec1((w >> 8) & 0xffu);
  o[2] = fp8_dec1((w >> 16) & 0xffu);
  o[3] = fp8_dec1(w >> 24);
#endif
}

static constexpr int TBLK = (K_ / 64) * (H_ / 64) * B_;    // 192 transpose blocks
static constexpr int SBLK = (L_ / 4) * B_;                 // 256 score blocks
static constexpr int CBLK = (VAL_SIZE_ * H_) / (256 * 16); // 1875 convert blocks

// ---------------------------------------------------------------------------
// Kernel 1: gather key embedding rows, transpose to bf16 ET16[b][h][k].
// grid TBLK, block 256.
// ---------------------------------------------------------------------------
__global__ __launch_bounds__(256)
void k_gather_keys_T(const int* __restrict__ key_seq,
                     const float* __restrict__ key_emb,
                     unsigned short* __restrict__ ET16) {
  __shared__ float tile[64][65];
  const int blk  = blockIdx.x;
  const int kb   = (blk % (K_ / 64)) * 64;
  const int hb   = ((blk / (K_ / 64)) % (H_ / 64)) * 64;
  const int b    = blk / ((K_ / 64) * (H_ / 64));
  const int t    = threadIdx.x;
  const int sub  = t >> 6;
  const int lane = t & 63;

#pragma unroll
  for (int p = 0; p < 16; ++p) {
    const int kl  = p * 4 + sub;
    const int row = key_seq[b * K_ + kb + kl];              // wave-uniform
    tile[kl][lane] = key_emb[(size_t)row * H_ + hb + lane]; // coalesced
  }
  __syncthreads();
#pragma unroll
  for (int p = 0; p < 16; ++p) {
    const int hl = p * 4 + sub;
    ET16[((size_t)b * H_ + hb + hl) * K_ + kb + lane] =
        (unsigned short)bf16_rne(tile[lane][hl]);
  }
}

// ---------------------------------------------------------------------------
// Kernel 2: scores + masked softmax (blocks [0,SBLK)); val-table f32->fp8
// conversion (blocks [SBLK, SBLK+CBLK)) rides the same grid so its HBM
// traffic overlaps the scores' L2/VALU work. block 256.
// ---------------------------------------------------------------------------
__global__ __launch_bounds__(256)
void k_scores_convert(const float* __restrict__ hidden,
                      const unsigned short* __restrict__ ET16,
                      const int* __restrict__ mask,
                      const float* __restrict__ vtab,
                      float* __restrict__ P,
                      unsigned char* __restrict__ VT8) {
  __shared__ float  hid[4 * H_];    // 12 KB
  __shared__ float4 part[4][256];   // 16 KB
  const int t = threadIdx.x;

  if (blockIdx.x >= SBLK) {
    // ---- val table f32 -> fp8, 16 elems/thread, exact-cover ----
    const size_t e0 = ((size_t)(blockIdx.x - SBLK) * 256 + t) * 16;
    const float4 a = *reinterpret_cast<const float4*>(vtab + e0);
    const float4 b = *reinterpret_cast<const float4*>(vtab + e0 + 4);
    const float4 c = *reinterpret_cast<const float4*>(vtab + e0 + 8);
    const float4 d = *reinterpret_cast<const float4*>(vtab + e0 + 12);
    uint4 o;
    o.x = fp8_enc4(a.x, a.y, a.z, a.w);
    o.y = fp8_enc4(b.x, b.y, b.z, b.w);
    o.z = fp8_enc4(c.x, c.y, c.z, c.w);
    o.w = fp8_enc4(d.x, d.y, d.z, d.w);
    *reinterpret_cast<uint4*>(VT8 + e0) = o;
    return;
  }

  const int l0 = (blockIdx.x % (L_ / 4)) * 4;
  const int b  = blockIdx.x / (L_ / 4);

  const float* hsrc = hidden + ((size_t)b * L_ + l0) * H_;
  for (int i = t; i < 4 * H_; i += 256) hid[i] = hsrc[i];
  __syncthreads();

  const int kq = t & 63;
  const int hq = t >> 6;

  float4 acc[4];
#pragma unroll
  for (int l = 0; l < 4; ++l) acc[l] = make_float4(0.f, 0.f, 0.f, 0.f);

  const unsigned short* etp =
      ET16 + (size_t)b * H_ * K_ + (size_t)(hq * 192) * K_ + kq * 4;
  const int hbase = hq * 192;
#pragma unroll 4
  for (int hh = 0; hh < 192; ++hh) {
    const uint2 e = *reinterpret_cast<const uint2*>(etp + (size_t)hh * K_);
    const float e0 = bf_lo(e.x), e1 = bf_hi(e.x);
    const float e2 = bf_lo(e.y), e3 = bf_hi(e.y);
#pragma unroll
    for (int l = 0; l < 4; ++l) {
      const float hv = hid[l * H_ + hbase + hh];  // LDS broadcast
      acc[l].x += hv * e0;
      acc[l].y += hv * e1;
      acc[l].z += hv * e2;
      acc[l].w += hv * e3;
    }
  }
#pragma unroll
  for (int l = 0; l < 4; ++l) part[l][t] = acc[l];
  __syncthreads();

  const int kq2 = t & 63;
  const int l2  = t >> 6;
  float4 a = part[l2][kq2];
  const float4 b1 = part[l2][64 + kq2];
  const float4 c  = part[l2][128 + kq2];
  const float4 d  = part[l2][192 + kq2];
  a.x += b1.x + c.x + d.x;
  a.y += b1.y + c.y + d.y;
  a.z += b1.z + c.z + d.z;
  a.w += b1.w + c.w + d.w;

  const int lrow = l0 + l2;
  const int4 m4 = *reinterpret_cast<const int4*>(
      mask + ((size_t)b * L_ + lrow) * K_ + kq2 * 4);
  float4 ex;
  ex.x = (m4.x > 0) ? expf(a.x * INV_TEMPER) : 0.f;
  ex.y = (m4.y > 0) ? expf(a.y * INV_TEMPER) : 0.f;
  ex.z = (m4.z > 0) ? expf(a.z * INV_TEMPER) : 0.f;
  ex.w = (m4.w > 0) ? expf(a.w * INV_TEMPER) : 0.f;

  float s = ex.x + ex.y + ex.z + ex.w;
#pragma unroll
  for (int off = 32; off > 0; off >>= 1) s += __shfl_down(s, off);
  const float tot = __shfl(s, 0) + 1e-10f;

  float4 p4;
  p4.x = ex.x / tot;
  p4.y = ex.y / tot;
  p4.z = ex.z / tot;
  p4.w = ex.w / tot;
  *reinterpret_cast<float4*>(P + ((size_t)b * L_ + lrow) * K_ + kq2 * 4) = p4;
}

// ---------------------------------------------------------------------------
// Kernel 3: o = sum_k p * V8[idx] + hidden, skipping p==0 via deterministic
// compaction. 4 slices x 96 lanes, uint2 (8B = 8 fp8) per lane; fp8 rows
// are 768 B -> half the gather traffic of bf16.
// grid (L, B), block 384.
// ---------------------------------------------------------------------------
__global__ __launch_bounds__(384)
void k_pv_add(const float* __restrict__ hidden,
              const int* __restrict__ vmat,
              const float* __restrict__ P,
              const unsigned char* __restrict__ VT8,
              float* __restrict__ out) {
  __shared__ float pw[K_];
  __shared__ int   vidx[K_];
  __shared__ int   wcounts[4];
  __shared__ float osum[3][H_];   // slices 0..2; slice 3 keeps regs

  const int l = blockIdx.x;
  const int b = blockIdx.y;
  const int t = threadIdx.x;
  const int lane = t & 63;
  const int wid  = t >> 6;
  const size_t rowoff = ((size_t)b * L_ + l) * K_;

  // deterministic compaction of nonzero p (waves 0..3 fully active)
  float pval = 0.f;
  bool pred = false;
  unsigned long long mball = 0;
  if (t < K_) {
    pval = P[rowoff + t];
    pred = (pval != 0.f);
    mball = __ballot(pred);
    if (lane == 0) wcounts[wid] = (int)__popcll(mball);
  }
  __syncthreads();
  const int n = wcounts[0] + wcounts[1] + wcounts[2] + wcounts[3];
  if (t < K_ && pred) {
    int base = 0;
#pragma unroll
    for (int w = 0; w < 4; ++w)
      if (w < wid) base += wcounts[w];
    const int pos = base + (int)__popcll(mball & ((1ull << lane) - 1ull));
    pw[pos]   = pval;
    vidx[pos] = vmat[rowoff + t];
  }
  __syncthreads();

  const int slice = t / 96;   // 0..3
  const int g     = t % 96;   // h-lane: h in [g*8, g*8+8)

  float acc[8];
#pragma unroll
  for (int i = 0; i < 8; ++i) acc[i] = 0.f;

#pragma unroll 4
  for (int j = slice; j < n; j += 4) {
    const float w = pw[j];                        // LDS broadcast
    const uint2 v = *reinterpret_cast<const uint2*>(
        VT8 + (size_t)vidx[j] * H_ + g * 8);      // 8B coalesced fp8
    float f[8];
    fp8_dec4(v.x, f);
    fp8_dec4(v.y, f + 4);
#pragma unroll
    for (int i = 0; i < 8; ++i) acc[i] += w * f[i];
  }

  if (slice < 3) {
    float4 lo  = make_float4(acc[0], acc[1], acc[2], acc[3]);
    float4 hi4 = make_float4(acc[4], acc[5], acc[6], acc[7]);
    *reinterpret_cast<float4*>(&osum[slice][g * 8])     = lo;
    *reinterpret_cast<float4*>(&osum[slice][g * 8 + 4]) = hi4;
  }
  __syncthreads();
  if (slice == 3) {
    const float* hrow = hidden + ((size_t)b * L_ + l) * H_ + g * 8;
    const float4 h0 = *reinterpret_cast<const float4*>(hrow);
    const float4 h1 = *reinterpret_cast<const float4*>(hrow + 4);
    float4 r0, r1;
    r0.x = acc[0] + osum[0][g*8+0] + osum[1][g*8+0] + osum[2][g*8+0] + h0.x;
    r0.y = acc[1] + osum[0][g*8+1] + osum[1][g*8+1] + osum[2][g*8+1] + h0.y;
    r0.z = acc[2] + osum[0][g*8+2] + osum[1][g*8+2] + osum[2][g*8+2] + h0.z;
    r0.w = acc[3] + osum[0][g*8+3] + osum[1][g*8+3] + osum[2][g*8+3] + h0.w;
    r1.x = acc[4] + osum[0][g*8+4] + osum[1][g*8+4] + osum[2][g*8+4] + h1.x;
    r1.y = acc[5] + osum[0][g*8+5] + osum[1][g*8+5] + osum[2][g*8+5] + h1.y;
    r1.z = acc[6] + osum[0][g*8+6] + osum[1][g*8+6] + osum[2][g*8+6] + h1.z;
    r1.w = acc[7] + osum[0][g*8+7] + osum[1][g*8+7] + osum[2][g*8+7] + h1.w;
    float* orow = out + ((size_t)b * L_ + l) * H_ + g * 8;
    *reinterpret_cast<float4*>(orow)     = r0;
    *reinterpret_cast<float4*>(orow + 4) = r1;
  }
}

// ---------------------------------------------------------------------------
extern "C" void kernel_launch(void* const* d_in, const int* in_sizes, int n_in,
                              void* d_out, int out_size, void* d_ws, size_t ws_size,
                              hipStream_t stream) {
  (void)in_sizes; (void)n_in; (void)out_size; (void)ws_size;
  const float* hidden  = (const float*)d_in[0];
  const int*   key_seq = (const int*)d_in[1];
  const int*   vmat    = (const int*)d_in[2];
  const int*   mask    = (const int*)d_in[3];
  const float* key_emb = (const float*)d_in[4];
  const float* val_emb = (const float*)d_in[5];
  float* out = (float*)d_out;

  // ws layout (16B-aligned):
  //   VT8 : VAL_SIZE*H bytes  = 7,680,000 B
  //   ET16: B*H*K ushort      = 1,572,864 B
  //   P   : B*L*K float       = 1,048,576 B
  unsigned char*  VT8  = (unsigned char*)d_ws;
  unsigned short* ET16 = (unsigned short*)(VT8 + (size_t)VAL_SIZE_ * H_);
  float*          P    = (float*)(ET16 + (size_t)B_ * H_ * K_);

  k_gather_keys_T<<<TBLK, 256, 0, stream>>>(key_seq, key_emb, ET16);
  k_scores_convert<<<SBLK + CBLK, 256, 0, stream>>>(hidden, ET16, mask,
                                                    val_emb, P, VT8);
  k_pv_add<<<dim3(L_, B_), 384, 0, stream>>>(hidden, vmat, P, VT8, out);
}